// Round 2
// baseline (176.733 us; speedup 1.0000x reference)
//
#include <hip/hip_runtime.h>
#include <math.h>

// RWKV WKV forward, chunked parallel scan v2.
// B=8, T=2048, H=768. Runtime-selected NC (chunks) by ws_size.
// ws layout: float4 state[B][NC][H] = {a, b, e, pad}.

#define B_   8
#define T_   2048
#define H_   768
#define TPB_ 192   // H_/4 threads; each thread owns 4 consecutive h channels

__device__ __forceinline__ float rcp_f(float x) { return __builtin_amdgcn_rcpf(x); }

// ---------------- Phase 1: per-chunk local aggregates ----------------
template <int NC>
__global__ __launch_bounds__(TPB_) void wkv_phase1(
    const float* __restrict__ key, const float* __restrict__ val,
    const float* __restrict__ time_decay, float4* __restrict__ ws)
{
    constexpr int L = T_ / NC;
    const int h0 = threadIdx.x * 4;
    const int c = blockIdx.x, b = blockIdx.y;

    const float4 td = *(const float4*)(time_decay + h0);
    const float w[4] = { -__expf(td.x), -__expf(td.y), -__expf(td.z), -__expf(td.w) };

    const size_t base = ((size_t)b * T_ + (size_t)c * L) * (H_ / 4) + (h0 >> 2);
    const float4* kp = (const float4*)key + base;
    const float4* vp = (const float4*)val + base;

    float a[4] = {0.f, 0.f, 0.f, 0.f};
    float bb[4] = {0.f, 0.f, 0.f, 0.f};
    float e[4] = {-INFINITY, -INFINITY, -INFINITY, -INFINITY};

    float4 kt = kp[0], vt = vp[0];
#pragma unroll 4
    for (int t = 0; t < L; ++t) {
        float4 kn, vn;
        if (t + 1 < L) {
            kn = kp[(size_t)(t + 1) * (H_ / 4)];
            vn = vp[(size_t)(t + 1) * (H_ / 4)];
        }
        const float kk[4] = {kt.x, kt.y, kt.z, kt.w};
        const float vv[4] = {vt.x, vt.y, vt.z, vt.w};
#pragma unroll
        for (int j = 0; j < 4; ++j) {
            const float ew = e[j] + w[j];
            const float m2 = fmaxf(ew, kk[j]);
            const float s1 = __expf(ew - m2);
            const float s2 = __expf(kk[j] - m2);
            a[j]  = fmaf(s1, a[j],  s2 * vv[j]);
            bb[j] = fmaf(s1, bb[j], s2);
            e[j]  = m2;
        }
        kt = kn; vt = vn;
    }

    const size_t off = ((size_t)b * NC + c) * H_ + h0;
#pragma unroll
    for (int j = 0; j < 4; ++j)
        ws[off + j] = make_float4(a[j], bb[j], e[j], 0.f);
}

// ---------------- Phase 2: sequential combine across chunks ----------------
// One thread per (b,h). Depth-P register prefetch ring over the chunk axis.
// Writes chunk c's INCOMING state in-place, then folds chunk c's aggregate.
template <int NC, int P>
__global__ __launch_bounds__(256) void wkv_phase2(
    float4* __restrict__ ws, const float* __restrict__ time_decay)
{
    constexpr int L = T_ / NC;
    const int idx = blockIdx.x * 256 + threadIdx.x;  // 0 .. B_*H_-1
    const int b = idx / H_;
    const int h = idx - b * H_;

    const float wL = -__expf(time_decay[h]) * (float)L;

    const size_t off0 = (size_t)b * NC * H_ + h;
    float4 ring[P];
#pragma unroll
    for (int p = 0; p < P; ++p) ring[p] = ws[off0 + (size_t)p * H_];

    float ra = 0.f, rb = 0.f, re = -INFINITY;
#pragma unroll 8
    for (int c = 0; c < NC; ++c) {
        const float4 cur = ring[c & (P - 1)];
        if (c + P < NC) ring[c & (P - 1)] = ws[off0 + (size_t)(c + P) * H_];
        ws[off0 + (size_t)c * H_] = make_float4(ra, rb, re, 0.f);

        const float e1 = re + wL;
        const float m  = fmaxf(e1, cur.z);
        const float p_ = __expf(e1 - m);
        const float q_ = __expf(cur.z - m);
        ra = fmaf(ra, p_, cur.x * q_);
        rb = fmaf(rb, p_, cur.y * q_);
        re = m;
    }
}

// ---------------- Phase 3: replay each chunk, emit wkv ----------------
template <int NC>
__global__ __launch_bounds__(TPB_) void wkv_phase3(
    const float* __restrict__ key, const float* __restrict__ val,
    const float* __restrict__ time_decay, const float* __restrict__ time_first,
    const float4* __restrict__ ws, float* __restrict__ out)
{
    constexpr int L = T_ / NC;
    const int h0 = threadIdx.x * 4;
    const int c = blockIdx.x, b = blockIdx.y;

    const float4 td = *(const float4*)(time_decay + h0);
    const float4 tf = *(const float4*)(time_first + h0);
    const float w[4] = { -__expf(td.x), -__expf(td.y), -__expf(td.z), -__expf(td.w) };
    const float u[4] = { tf.x, tf.y, tf.z, tf.w };

    const size_t soff = ((size_t)b * NC + c) * H_ + h0;
    float a[4], bb[4], e[4];
#pragma unroll
    for (int j = 0; j < 4; ++j) {
        const float4 s = ws[soff + j];
        a[j] = s.x; bb[j] = s.y; e[j] = s.z;
    }

    const size_t base = ((size_t)b * T_ + (size_t)c * L) * (H_ / 4) + (h0 >> 2);
    const float4* kp = (const float4*)key + base;
    const float4* vp = (const float4*)val + base;
    float4*       op = (float4*)out + base;

    float4 kt = kp[0], vt = vp[0];
#pragma unroll 4
    for (int t = 0; t < L; ++t) {
        float4 kn, vn;
        if (t + 1 < L) {
            kn = kp[(size_t)(t + 1) * (H_ / 4)];
            vn = vp[(size_t)(t + 1) * (H_ / 4)];
        }
        const float kk[4] = {kt.x, kt.y, kt.z, kt.w};
        const float vv[4] = {vt.x, vt.y, vt.z, vt.w};
        float o[4];
#pragma unroll
        for (int j = 0; j < 4; ++j) {
            // wkv output (state BEFORE update)
            const float uk = u[j] + kk[j];
            const float m1 = fmaxf(e[j], uk);
            const float wt = __expf(uk - m1);
            const float sc = __expf(e[j] - m1);
            const float num = fmaf(a[j],  sc, wt * vv[j]);
            const float den = fmaf(bb[j], sc, wt);
            o[j] = num * rcp_f(den);

            // state update
            const float ew = e[j] + w[j];
            const float m2 = fmaxf(ew, kk[j]);
            const float s1 = __expf(ew - m2);
            const float s2 = __expf(kk[j] - m2);
            a[j]  = fmaf(s1, a[j],  s2 * vv[j]);
            bb[j] = fmaf(s1, bb[j], s2);
            e[j]  = m2;
        }
        op[(size_t)t * (H_ / 4)] = make_float4(o[0], o[1], o[2], o[3]);
        kt = kn; vt = vn;
    }
}

// ---------------- launcher ----------------
template <int NC>
static void launch_all(const float* key, const float* val, const float* td,
                       const float* tf, float* out, float4* ws, hipStream_t stream)
{
    dim3 blk13(TPB_);
    dim3 grid13(NC, B_);
    wkv_phase1<NC><<<grid13, blk13, 0, stream>>>(key, val, td, ws);

    dim3 grid2((B_ * H_) / 256);
    wkv_phase2<NC, 8><<<grid2, dim3(256), 0, stream>>>(ws, td);

    wkv_phase3<NC><<<grid13, blk13, 0, stream>>>(key, val, td, tf, ws, out);
}

extern "C" void kernel_launch(void* const* d_in, const int* in_sizes, int n_in,
                              void* d_out, int out_size, void* d_ws, size_t ws_size,
                              hipStream_t stream) {
    const float* key = (const float*)d_in[0];
    const float* val = (const float*)d_in[1];
    const float* td  = (const float*)d_in[2];
    const float* tf  = (const float*)d_in[3];
    float* out = (float*)d_out;
    float4* ws = (float4*)d_ws;

    const size_t need128 = (size_t)B_ * 128 * H_ * sizeof(float4);
    const size_t need64  = (size_t)B_ * 64  * H_ * sizeof(float4);
    const size_t need32  = (size_t)B_ * 32  * H_ * sizeof(float4);

    if (ws_size >= need128)      launch_all<128>(key, val, td, tf, out, ws, stream);
    else if (ws_size >= need64)  launch_all<64>(key, val, td, tf, out, ws, stream);
    else if (ws_size >= need32)  launch_all<32>(key, val, td, tf, out, ws, stream);
    else                         launch_all<16>(key, val, td, tf, out, ws, stream);
}